// Round 11
// baseline (1820.042 us; speedup 1.0000x reference)
//
#include <hip/hip_runtime.h>

#define HW 147456
#define WID 384
#define NB 8
#define NPC 1179648   // per-channel element count = 8*384*384
#define HW4 36864     // HW/4
#define ZS 76         // zt/dH LDS row stride (mult of 4; 2-row conv offsets hit distinct banks)

static __device__ __forceinline__ float lrelu01(float v) { return v >= 0.f ? v : 0.01f * v; }
static __device__ __forceinline__ float mlrelu(float v) { return v > 0.1f ? 0.1f + 0.7f * (v - 0.1f) : v; }

// ---------------------------------------------------------------------------
// Mode pool: quantize x to 17 bins, 11x11 window mode (zero pad -> bin 0),
// first-max tie break. Grid (6,24,24), block 256.
// ---------------------------------------------------------------------------
__global__ __launch_bounds__(256) void mode_kernel(const float* __restrict__ x,
                                                   float* __restrict__ xm) {
  __shared__ unsigned char qt[26 * 76];
  __shared__ unsigned int cc[16 * 5 * 76];
  const int plane = blockIdx.z;
  const int x0 = blockIdx.x * 64;
  const int y0 = blockIdx.y * 16;
  const float* xp = x + (size_t)plane * HW;

  for (int i = threadIdx.x; i < 26 * 76; i += 256) {
    int r = i / 76, ccol = i - r * 76;
    int gy = y0 + r - 5, gx = x0 + ccol - 5;
    unsigned char q = 0;
    if (ccol < 74 && gy >= 0 && gy < WID && gx >= 0 && gx < WID) {
      float v = xp[gy * WID + gx];
      int qi = (int)rintf(v * 15.9375f);
      qi = qi < 0 ? 0 : (qi > 16 ? 16 : qi);
      q = (unsigned char)qi;
    }
    qt[i] = q;
  }
  __syncthreads();

  for (int i = threadIdx.x; i < 16 * 74; i += 256) {
    int yy = i / 74, col = i - yy * 74;
    unsigned int w0 = 0, w1 = 0, w2 = 0, w3 = 0, w4 = 0;
#pragma unroll
    for (int dy = 0; dy < 11; ++dy) {
      int q = qt[(yy + dy) * 76 + col];
      unsigned int inc = 1u << ((q & 3) << 3);
      int wsel = q >> 2;
      w0 += (wsel == 0) ? inc : 0u;
      w1 += (wsel == 1) ? inc : 0u;
      w2 += (wsel == 2) ? inc : 0u;
      w3 += (wsel == 3) ? inc : 0u;
      w4 += (wsel == 4) ? inc : 0u;
    }
    cc[(yy * 5 + 0) * 76 + col] = w0;
    cc[(yy * 5 + 1) * 76 + col] = w1;
    cc[(yy * 5 + 2) * 76 + col] = w2;
    cc[(yy * 5 + 3) * 76 + col] = w3;
    cc[(yy * 5 + 4) * 76 + col] = w4;
  }
  __syncthreads();

  for (int i = threadIdx.x; i < 16 * 64; i += 256) {
    int yy = i / 64, xx = i - yy * 64;
    unsigned int s0 = 0, s1 = 0, s2 = 0, s3 = 0, s4 = 0;
#pragma unroll
    for (int dx = 0; dx < 11; ++dx) {
      int col = xx + dx;
      s0 += cc[(yy * 5 + 0) * 76 + col];
      s1 += cc[(yy * 5 + 1) * 76 + col];
      s2 += cc[(yy * 5 + 2) * 76 + col];
      s3 += cc[(yy * 5 + 3) * 76 + col];
      s4 += cc[(yy * 5 + 4) * 76 + col];
    }
    unsigned int words[5] = {s0, s1, s2, s3, s4};
    int best = 0;
    unsigned int bc = s0 & 0xffu;
#pragma unroll
    for (int bin = 1; bin < 17; ++bin) {
      unsigned int cnt = (words[bin >> 2] >> ((bin & 3) * 8)) & 0xffu;
      if (cnt > bc) { bc = cnt; best = bin; }
    }
    xm[(size_t)plane * HW + (size_t)(y0 + yy) * WID + (x0 + xx)] = best * 0.0625f;
  }
}

// ---------------------------------------------------------------------------
// xm second moments: 3 sums + 6 cross-products, float4. grid 256.
// ---------------------------------------------------------------------------
__global__ __launch_bounds__(256) void xm_mom(const float4* __restrict__ X,
                                              float* __restrict__ part9) {
  float s0 = 0, s1 = 0, s2 = 0, m00 = 0, m01 = 0, m02 = 0, m11 = 0, m12 = 0, m22 = 0;
  const int end = (blockIdx.x + 1) * 1152;
  for (int u = blockIdx.x * 1152 + threadIdx.x; u < end; u += 256) {
    int b = u / HW4, p4 = u - b * HW4;
    const float4* base = X + (size_t)b * 3 * HW4 + p4;
    float4 a = base[0], bb = base[HW4], c = base[2 * HW4];
    s0 += a.x + a.y + a.z + a.w;
    s1 += bb.x + bb.y + bb.z + bb.w;
    s2 += c.x + c.y + c.z + c.w;
    m00 += a.x * a.x + a.y * a.y + a.z * a.z + a.w * a.w;
    m01 += a.x * bb.x + a.y * bb.y + a.z * bb.z + a.w * bb.w;
    m02 += a.x * c.x + a.y * c.y + a.z * c.z + a.w * c.w;
    m11 += bb.x * bb.x + bb.y * bb.y + bb.z * bb.z + bb.w * bb.w;
    m12 += bb.x * c.x + bb.y * c.y + bb.z * c.z + bb.w * c.w;
    m22 += c.x * c.x + c.y * c.y + c.z * c.z + c.w * c.w;
  }
  float vals[9] = {s0, s1, s2, m00, m01, m02, m11, m12, m22};
  int lane = threadIdx.x & 63, wd = threadIdx.x >> 6;
  __shared__ float red[4][9];
#pragma unroll
  for (int j = 0; j < 9; ++j) {
    float v = vals[j];
    for (int off = 32; off; off >>= 1) v += __shfl_down(v, off);
    if (lane == 0) red[wd][j] = v;
  }
  __syncthreads();
  if (threadIdx.x < 9)
    part9[blockIdx.x * 9 + threadIdx.x] =
        red[0][threadIdx.x] + red[1][threadIdx.x] + red[2][threadIdx.x] + red[3][threadIdx.x];
}

// ---------------------------------------------------------------------------
// analytic BN1 affine from xm moments
// ---------------------------------------------------------------------------
__global__ __launch_bounds__(64) void prep1_affine(const float* __restrict__ part9,
                                                   const float* __restrict__ w1,
                                                   const float* __restrict__ b1,
                                                   const float* __restrict__ dw1,
                                                   const float* __restrict__ db1,
                                                   const float* __restrict__ g,
                                                   const float* __restrict__ be,
                                                   float* __restrict__ sc,
                                                   float* __restrict__ sh) {
  __shared__ double M[9];
  if (threadIdx.x < 9) {
    double s = 0.0;
    for (int i = 0; i < 256; ++i) s += (double)part9[i * 9 + threadIdx.x];
    M[threadIdx.x] = s;
  }
  __syncthreads();
  if (threadIdx.x < 32) {
    int o = threadIdx.x;
    double dw = dw1[o];
    double a0 = (double)w1[o * 3] * dw, a1 = (double)w1[o * 3 + 1] * dw,
           a2 = (double)w1[o * 3 + 2] * dw;
    double k = (double)b1[o] * dw + (double)db1[o];
    double N = (double)NPC;
    double lin = (a0 * M[0] + a1 * M[1] + a2 * M[2]) / N;
    double mean = lin + k;
    double e2 = (a0 * a0 * M[3] + a1 * a1 * M[6] + a2 * a2 * M[8] +
                 2.0 * (a0 * a1 * M[4] + a0 * a2 * M[5] + a1 * a2 * M[7])) / N +
                2.0 * k * lin + k * k;
    double var = e2 - mean * mean;
    float rstd = rsqrtf((float)var + 1e-5f);
    float scl = rstd * g[o];
    sc[o] = scl;
    sh[o] = be[o] - (float)mean * scl;
  }
}

// ---------------------------------------------------------------------------
// fused prepare: conv1+BN1+lrelu folded, conv2 folded with dw2,
// writes t2 + fused raw-stats partials. 2 px/thread, grid 2304.
// ---------------------------------------------------------------------------
__global__ __launch_bounds__(256) void prep_fused(const float* __restrict__ xm,
                                                  const float* __restrict__ w1,
                                                  const float* __restrict__ b1,
                                                  const float* __restrict__ dw1,
                                                  const float* __restrict__ db1,
                                                  const float* __restrict__ P1SC,
                                                  const float* __restrict__ P1SH,
                                                  const float* __restrict__ w2,
                                                  const float* __restrict__ b2,
                                                  const float* __restrict__ dw2,
                                                  const float* __restrict__ db2,
                                                  float* __restrict__ t2,
                                                  float* __restrict__ part) {
  __shared__ float wl[1024];
  __shared__ float c1[32][4];
  __shared__ float bias2[32];
  __shared__ float wred[8][32];
  for (int i = threadIdx.x; i < 1024; i += 256) wl[i] = w2[i] * dw2[i >> 5];
  if (threadIdx.x < 32) {
    int o = threadIdx.x;
    float dw = dw1[o], s1 = P1SC[o];
    c1[o][0] = w1[o * 3] * dw * s1;
    c1[o][1] = w1[o * 3 + 1] * dw * s1;
    c1[o][2] = w1[o * 3 + 2] * dw * s1;
    c1[o][3] = (b1[o] * dw + db1[o]) * s1 + P1SH[o];
    bias2[o] = b2[o] * dw2[o] + db2[o];
  }
  __syncthreads();
  const int p0 = blockIdx.x * 512 + threadIdx.x;
  const int b = p0 / HW, pp = p0 - b * HW;
  const float* xb = xm + (size_t)b * 3 * HW + pp;
  float h[2][32];
#pragma unroll
  for (int q = 0; q < 2; ++q) {
    float x0 = xb[q * 256], x1 = xb[HW + q * 256], x2 = xb[2 * HW + q * 256];
#pragma unroll
    for (int o = 0; o < 32; ++o) {
      float u = fmaf(x0, c1[o][0], fmaf(x1, c1[o][1], fmaf(x2, c1[o][2], c1[o][3])));
      h[q][o] = lrelu01(u);
    }
  }
  float sv[32], sq[32];
  float* ob = t2 + (size_t)b * 32 * HW + pp;
  const float4* wl4 = reinterpret_cast<const float4*>(wl);
  for (int o = 0; o < 32; ++o) {
    float acc0 = bias2[o], acc1 = bias2[o];
#pragma unroll
    for (int c4 = 0; c4 < 8; ++c4) {
      float4 w4 = wl4[o * 8 + c4];
      int c = c4 * 4;
      acc0 = fmaf(h[0][c], w4.x, acc0);     acc1 = fmaf(h[1][c], w4.x, acc1);
      acc0 = fmaf(h[0][c + 1], w4.y, acc0); acc1 = fmaf(h[1][c + 1], w4.y, acc1);
      acc0 = fmaf(h[0][c + 2], w4.z, acc0); acc1 = fmaf(h[1][c + 2], w4.z, acc1);
      acc0 = fmaf(h[0][c + 3], w4.w, acc0); acc1 = fmaf(h[1][c + 3], w4.w, acc1);
    }
    ob[(size_t)o * HW] = acc0;
    ob[(size_t)o * HW + 256] = acc1;
    sv[o] = acc0 + acc1;
    sq[o] = acc0 * acc0 + acc1 * acc1;
  }
  int lane = threadIdx.x & 63, wd = threadIdx.x >> 6;
#pragma unroll
  for (int o = 0; o < 32; ++o) {
    float a = sv[o], q = sq[o];
    for (int off = 32; off; off >>= 1) {
      a += __shfl_down(a, off);
      q += __shfl_down(q, off);
    }
    if (lane == 0) { wred[wd][o] = a; wred[wd + 4][o] = q; }
  }
  __syncthreads();
  if (threadIdx.x < 32) {
    int o = threadIdx.x;
    part[((size_t)o * 2304 + blockIdx.x) * 2] = wred[0][o] + wred[1][o] + wred[2][o] + wred[3][o];
    part[((size_t)o * 2304 + blockIdx.x) * 2 + 1] = wred[4][o] + wred[5][o] + wred[6][o] + wred[7][o];
  }
}

// ---------------------------------------------------------------------------
// combine partials -> folded affine
// ---------------------------------------------------------------------------
__global__ __launch_bounds__(64) void stats_combine(const float* __restrict__ part, int nsplit,
                                                    const float* __restrict__ g,
                                                    const float* __restrict__ be,
                                                    float* __restrict__ sc,
                                                    float* __restrict__ sh) {
  const int c = blockIdx.x;
  double s = 0.0, q = 0.0;
  for (int i = threadIdx.x; i < nsplit; i += 64) {
    s += part[((size_t)c * nsplit + i) * 2];
    q += part[((size_t)c * nsplit + i) * 2 + 1];
  }
  for (int off = 32; off; off >>= 1) {
    s += __shfl_down(s, off);
    q += __shfl_down(q, off);
  }
  if (threadIdx.x == 0) {
    double mean = s / (double)NPC;
    double var = q / (double)NPC - mean * mean;
    float rstd = rsqrtf((float)var + 1e-5f);
    float scl = rstd * g[c];
    sc[c] = scl;
    sh[c] = be[c] - (float)mean * scl;
  }
}

// ---------------------------------------------------------------------------
// shared depthwise 3x3 stride-3 pad-1 conv; optional bn+lrelu on input
// ---------------------------------------------------------------------------
template <bool AFF>
__global__ __launch_bounds__(256) void dconv(const float* __restrict__ in,
                                             const float* __restrict__ sc,
                                             const float* __restrict__ sh,
                                             const float* __restrict__ w9,
                                             const float* __restrict__ db,
                                             int Sin, int Sout,
                                             float* __restrict__ out, int total) {
  int idx = blockIdx.x * 256 + threadIdx.x;
  if (idx >= total) return;
  int xx = idx % Sout;
  int t = idx / Sout;
  int yy = t % Sout;
  int pc = t / Sout;
  int c = pc & 31;
  const float* ip = in + (size_t)pc * Sin * Sin;
  float a = AFF ? sc[c] : 1.f;
  float h = AFF ? sh[c] : 0.f;
  float acc = 0.f;
#pragma unroll
  for (int ky = 0; ky < 3; ++ky) {
    int iy = 3 * yy - 1 + ky;
    if (iy < 0 || iy >= Sin) continue;
#pragma unroll
    for (int kx = 0; kx < 3; ++kx) {
      int ix = 3 * xx - 1 + kx;
      if (ix < 0 || ix >= Sin) continue;
      float v = ip[(size_t)iy * Sin + ix];
      if (AFF) { v = v * a + h; v = lrelu01(v); }
      acc = fmaf(v, w9[ky * 3 + kx], acc);
    }
  }
  out[idx] = acc + db[0];
}

// ---------------------------------------------------------------------------
// pyramid: global packed geometry table geo[l][384] = (i0, i1, frac, 0)
// ---------------------------------------------------------------------------
static __device__ __forceinline__ int sin_of(int l) {
  return l == 0 ? 128 : l == 1 ? 43 : l == 2 ? 15 : l == 3 ? 5 : 2;
}

__global__ __launch_bounds__(256) void geo_build(float4* __restrict__ geo) {
  int id = blockIdx.x * 256 + threadIdx.x;
  if (id >= 5 * 384) return;
  int l = id / 384, p = id - l * 384;
  int Sin = sin_of(l);
  float scale = (float)Sin / 384.f;
  float s = (p + 0.5f) * scale - 0.5f;
  float f0 = floorf(s);
  float fr = s - f0;
  int ii = (int)f0;
  int i1 = ii + 1 < Sin - 1 ? ii + 1 : Sin - 1;
  int i0 = ii > 0 ? ii : 0;
  geo[id] = make_float4((float)i0, (float)i1, fr, 0.f);
}

static __device__ __forceinline__ int clamp383(int v) {
  return v < 0 ? 0 : (v > 383 ? 383 : v);
}

// 2-row streaming 5x5 conv on zt rows 2u..2u+5, cols g*4..g*4+7 (stride ZS).
__device__ __forceinline__ void conv2row(const float* zt, int u, int g,
                                         const float* wa, const float* wb,
                                         float ba0, float bb0,
                                         float* A0, float* A1, float* B0, float* B1) {
#pragma unroll
  for (int j = 0; j < 4; ++j) { A0[j] = ba0; A1[j] = ba0; B0[j] = bb0; B1[j] = bb0; }
  const float* zp = zt + (2 * u) * ZS + g * 4;
#pragma unroll
  for (int zr = 0; zr < 6; ++zr) {
    float4 zlo = *reinterpret_cast<const float4*>(zp + zr * ZS);
    float4 zhi = *reinterpret_cast<const float4*>(zp + zr * ZS + 4);
    float z[8] = {zlo.x, zlo.y, zlo.z, zlo.w, zhi.x, zhi.y, zhi.z, zhi.w};
    if (zr < 5) {
#pragma unroll
      for (int dx = 0; dx < 5; ++dx) {
        float wva = wa[zr * 5 + dx], wvb = wb[zr * 5 + dx];
#pragma unroll
        for (int j = 0; j < 4; ++j) {
          A0[j] = fmaf(z[dx + j], wva, A0[j]);
          B0[j] = fmaf(z[dx + j], wvb, B0[j]);
        }
      }
    }
    if (zr >= 1) {
#pragma unroll
      for (int dx = 0; dx < 5; ++dx) {
        float wva = wa[(zr - 1) * 5 + dx], wvb = wb[(zr - 1) * 5 + dx];
#pragma unroll
        for (int j = 0; j < 4; ++j) {
          A1[j] = fmaf(z[dx + j], wva, A1[j]);
          B1[j] = fmaf(z[dx + j], wvb, B1[j]);
        }
      }
    }
  }
}

// ---------------------------------------------------------------------------
// pyramid stats: 64x32 tile, 2 planes/block, global geo. grid (72, 128, 5).
// ---------------------------------------------------------------------------
__global__ __launch_bounds__(256) void upstats64(const float* __restrict__ d1,
                                                 const float* __restrict__ d2,
                                                 const float* __restrict__ d3,
                                                 const float* __restrict__ d4,
                                                 const float* __restrict__ d5,
                                                 const float4* __restrict__ geo,
                                                 const float* __restrict__ wA5,
                                                 const float* __restrict__ wB5,
                                                 const float* __restrict__ bA,
                                                 const float* __restrict__ bB,
                                                 float* __restrict__ partA,
                                                 float* __restrict__ partB) {
  __shared__ __align__(16) float zt[2][36 * ZS];
  __shared__ __align__(16) float dH[2][16 * ZS];
  __shared__ float red[2][16];
  const int lvl = blockIdx.z;
  const float* dsel = lvl == 0 ? d1 : lvl == 1 ? d2 : lvl == 2 ? d3 : lvl == 3 ? d4 : d5;
  const int Sin = sin_of(lvl);
  const int plane0 = blockIdx.y * 2, tile = blockIdx.x;
  const int tx = (tile % 6) * 64, ty = (tile / 6) * 32;
  const float4* xg = geo + lvl * 384;
  const float* dp0 = dsel + (size_t)plane0 * Sin * Sin;
  const float* dp1 = dp0 + Sin * Sin;

  float wa[25], wb[25];
#pragma unroll
  for (int k = 0; k < 25; ++k) { wa[k] = wA5[k]; wb[k] = wB5[k]; }
  const float ba0 = bA[0], bb0 = bB[0];

  const int rowlo = (int)xg[clamp383(ty - 2)].x;
  const int rowhi = (int)xg[clamp383(ty + 33)].y;
  const int nr = rowhi - rowlo + 1;
  const int cnt = nr * 68;

  // x-interp both planes
  for (int i = threadIdx.x; i < 2 * cnt; i += 256) {
    int p = i < cnt ? 0 : 1;
    int j = i - p * cnt;
    int r = j / 68, zx = j - r * 68;
    int gp = tx + zx - 2;
    int gpc = clamp383(gp);
    float vd = (gp == gpc) ? 1.f : 0.f;
    float4 ge = xg[gpc];
    const float* drow = (p ? dp1 : dp0) + (size_t)(rowlo + r) * Sin;
    float v0 = drow[(int)ge.x], v1 = drow[(int)ge.y];
    dH[p][r * ZS + zx] = (v0 + ge.z * (v1 - v0)) * vd;
  }
  __syncthreads();
  // y-interp both planes (17 float4 groups x 36 rows)
  for (int i = threadIdx.x; i < 2 * 612; i += 256) {
    int p = i < 612 ? 0 : 1;
    int j = i - p * 612;
    int zy = j / 17, k = j - zy * 17;
    int gp = ty + zy - 2;
    int gpc = clamp383(gp);
    float vd = (gp == gpc) ? 1.f : 0.f;
    float4 ge = xg[gpc];
    int r0 = (int)ge.x - rowlo, r1 = (int)ge.y - rowlo;
    float fy = ge.z;
    float4 a4 = *reinterpret_cast<const float4*>(&dH[p][r0 * ZS + k * 4]);
    float4 b4 = *reinterpret_cast<const float4*>(&dH[p][r1 * ZS + k * 4]);
    float4 o;
    o.x = (a4.x + fy * (b4.x - a4.x)) * vd;
    o.y = (a4.y + fy * (b4.y - a4.y)) * vd;
    o.z = (a4.z + fy * (b4.z - a4.z)) * vd;
    o.w = (a4.w + fy * (b4.w - a4.w)) * vd;
    *reinterpret_cast<float4*>(&zt[p][zy * ZS + k * 4]) = o;
  }
  __syncthreads();

  const int u = threadIdx.x >> 4, g = threadIdx.x & 15;
  const int lane = threadIdx.x & 63, wd = threadIdx.x >> 6;
#pragma unroll
  for (int p = 0; p < 2; ++p) {
    float A0[4], A1[4], B0[4], B1[4];
    conv2row(zt[p], u, g, wa, wb, ba0, bb0, A0, A1, B0, B1);
    float sa = 0.f, qa = 0.f, sb = 0.f, qb = 0.f;
#pragma unroll
    for (int j = 0; j < 4; ++j) {
      sa += A0[j] + A1[j];
      qa += A0[j] * A0[j] + A1[j] * A1[j];
      sb += B0[j] + B1[j];
      qb += B0[j] * B0[j] + B1[j] * B1[j];
    }
    for (int off = 32; off; off >>= 1) {
      sa += __shfl_down(sa, off); qa += __shfl_down(qa, off);
      sb += __shfl_down(sb, off); qb += __shfl_down(qb, off);
    }
    if (lane == 0) {
      red[p][wd * 4 + 0] = sa; red[p][wd * 4 + 1] = qa;
      red[p][wd * 4 + 2] = sb; red[p][wd * 4 + 3] = qb;
    }
  }
  __syncthreads();
  if (threadIdx.x < 2) {
    int p = threadIdx.x;
    int plane = plane0 + p;
    int b = plane >> 5, c = plane & 31;
    const float* r_ = red[p];
    size_t pi = ((size_t)lvl * 32 + c) * 576 * 2 + ((size_t)b * 72 + tile) * 2;
    partA[pi] = r_[0] + r_[4] + r_[8] + r_[12];
    partA[pi + 1] = r_[1] + r_[5] + r_[9] + r_[13];
    partB[pi] = r_[2] + r_[6] + r_[10] + r_[14];
    partB[pi + 1] = r_[3] + r_[7] + r_[11] + r_[15];
  }
}

// combine all 10 (level, conv) BN affines. grid (32, 5, 2). entries=576.
__global__ __launch_bounds__(64) void combine_lvls(const float* __restrict__ partA,
                                                   const float* __restrict__ partB,
                                                   const float* __restrict__ ia_g,
                                                   const float* __restrict__ ia_be,
                                                   const float* __restrict__ ib_g,
                                                   const float* __restrict__ ib_be,
                                                   float* __restrict__ aff) {
  const int c = blockIdx.x, lvl = blockIdx.y, z = blockIdx.z;
  const float* part = (z ? partB : partA) + (size_t)lvl * 32 * 576 * 2;
  const float* g = z ? ib_g : ia_g;
  const float* be = z ? ib_be : ia_be;
  double s = 0.0, q = 0.0;
  for (int i = threadIdx.x; i < 576; i += 64) {
    s += part[((size_t)c * 576 + i) * 2];
    q += part[((size_t)c * 576 + i) * 2 + 1];
  }
  for (int off = 32; off; off >>= 1) {
    s += __shfl_down(s, off);
    q += __shfl_down(q, off);
  }
  if (threadIdx.x == 0) {
    double mean = s / (double)NPC;
    double var = q / (double)NPC - mean * mean;
    float rstd = rsqrtf((float)var + 1e-5f);
    float scl = rstd * g[c];
    aff[((z * 5 + lvl) * 2 + 0) * 32 + c] = scl;
    aff[((z * 5 + lvl) * 2 + 1) * 32 + c] = be[c] - (float)mean * scl;
  }
}

// ---------------------------------------------------------------------------
// apply ALL 5 levels: 64x32 tile, 8 px/thread, global geo. grid (72, 256).
// ---------------------------------------------------------------------------
__global__ __launch_bounds__(256) void apply64(const float* __restrict__ d1,
                                               const float* __restrict__ d2,
                                               const float* __restrict__ d3,
                                               const float* __restrict__ d4,
                                               const float* __restrict__ d5,
                                               const float4* __restrict__ geo,
                                               const float* __restrict__ wA5,
                                               const float* __restrict__ wB5,
                                               const float* __restrict__ bA,
                                               const float* __restrict__ bB,
                                               const float* __restrict__ aff,
                                               float* __restrict__ outp,
                                               float* __restrict__ partF) {
  __shared__ __align__(16) float zt[36 * ZS];
  __shared__ __align__(16) float dH[16 * ZS];
  __shared__ float red[16];
  const int plane = blockIdx.y, tile = blockIdx.x;
  const int tx = (tile % 6) * 64, ty = (tile / 6) * 32;
  const int b = plane >> 5, c = plane & 31;
  float wa[25], wb[25];
#pragma unroll
  for (int k = 0; k < 25; ++k) { wa[k] = wA5[k]; wb[k] = wB5[k]; }
  const float ba0 = bA[0], bb0 = bB[0];
  const int u = threadIdx.x >> 4, g = threadIdx.x & 15;

  float acA0[4] = {0, 0, 0, 0}, acA1[4] = {0, 0, 0, 0};
  float acB0[4] = {0, 0, 0, 0}, acB1[4] = {0, 0, 0, 0};

  for (int l = 0; l < 5; ++l) {
    const float* dsel = l == 0 ? d1 : l == 1 ? d2 : l == 2 ? d3 : l == 3 ? d4 : d5;
    const int Sin = sin_of(l);
    const float* dp = dsel + (size_t)plane * Sin * Sin;
    const float4* xg = geo + l * 384;
    const int rowlo = (int)xg[clamp383(ty - 2)].x;
    const int rowhi = (int)xg[clamp383(ty + 33)].y;
    const int nr = rowhi - rowlo + 1;
    // x-interp (dH free: prior y-interp consumed it before last barrier)
    for (int i = threadIdx.x; i < nr * 68; i += 256) {
      int r = i / 68, zx = i - r * 68;
      int gp = tx + zx - 2;
      int gpc = clamp383(gp);
      float vd = (gp == gpc) ? 1.f : 0.f;
      float4 ge = xg[gpc];
      const float* drow = dp + (size_t)(rowlo + r) * Sin;
      float v0 = drow[(int)ge.x], v1 = drow[(int)ge.y];
      dH[r * ZS + zx] = (v0 + ge.z * (v1 - v0)) * vd;
    }
    __syncthreads();
    // y-interp (zt free: all threads finished prior conv to reach this point)
    for (int i = threadIdx.x; i < 612; i += 256) {
      int zy = i / 17, k = i - zy * 17;
      int gp = ty + zy - 2;
      int gpc = clamp383(gp);
      float vd = (gp == gpc) ? 1.f : 0.f;
      float4 ge = xg[gpc];
      int r0 = (int)ge.x - rowlo, r1 = (int)ge.y - rowlo;
      float fy = ge.z;
      float4 a4 = *reinterpret_cast<const float4*>(&dH[r0 * ZS + k * 4]);
      float4 b4 = *reinterpret_cast<const float4*>(&dH[r1 * ZS + k * 4]);
      float4 o;
      o.x = (a4.x + fy * (b4.x - a4.x)) * vd;
      o.y = (a4.y + fy * (b4.y - a4.y)) * vd;
      o.z = (a4.z + fy * (b4.z - a4.z)) * vd;
      o.w = (a4.w + fy * (b4.w - a4.w)) * vd;
      *reinterpret_cast<float4*>(&zt[zy * ZS + k * 4]) = o;
    }
    __syncthreads();
    float A0[4], A1[4], B0[4], B1[4];
    conv2row(zt, u, g, wa, wb, ba0, bb0, A0, A1, B0, B1);
    float as = aff[(l * 2 + 0) * 32 + c], ah = aff[(l * 2 + 1) * 32 + c];
    float bs = aff[((5 + l) * 2 + 0) * 32 + c], bh = aff[((5 + l) * 2 + 1) * 32 + c];
#pragma unroll
    for (int j = 0; j < 4; ++j) {
      acA0[j] += lrelu01(fmaf(A0[j], as, ah));
      acA1[j] += lrelu01(fmaf(A1[j], as, ah));
      acB0[j] += lrelu01(fmaf(B0[j], bs, bh));
      acB1[j] += lrelu01(fmaf(B1[j], bs, bh));
    }
  }

  float4 xa0 = {acA0[0], acA0[1], acA0[2], acA0[3]};
  float4 xa1 = {acA1[0], acA1[1], acA1[2], acA1[3]};
  float4 xb0 = {acB0[0], acB0[1], acB0[2], acB0[3]};
  float4 xb1 = {acB1[0], acB1[1], acB1[2], acB1[3]};
  size_t po = (size_t)(b * 64 + c) * HW + (size_t)(ty + 2 * u) * WID + tx + g * 4;
  *reinterpret_cast<float4*>(outp + po) = xa0;
  *reinterpret_cast<float4*>(outp + po + WID) = xa1;
  *reinterpret_cast<float4*>(outp + po + (size_t)32 * HW) = xb0;
  *reinterpret_cast<float4*>(outp + po + (size_t)32 * HW + WID) = xb1;

  float sa = 0.f, qa = 0.f, sb = 0.f, qb = 0.f;
#pragma unroll
  for (int j = 0; j < 4; ++j) {
    sa += acA0[j] + acA1[j];
    qa += acA0[j] * acA0[j] + acA1[j] * acA1[j];
    sb += acB0[j] + acB1[j];
    qb += acB0[j] * acB0[j] + acB1[j] * acB1[j];
  }
  int lane = threadIdx.x & 63, wd = threadIdx.x >> 6;
  for (int off = 32; off; off >>= 1) {
    sa += __shfl_down(sa, off); qa += __shfl_down(qa, off);
    sb += __shfl_down(sb, off); qb += __shfl_down(qb, off);
  }
  if (lane == 0) {
    red[wd * 4 + 0] = sa; red[wd * 4 + 1] = qa;
    red[wd * 4 + 2] = sb; red[wd * 4 + 3] = qb;
  }
  __syncthreads();
  if (threadIdx.x == 0) {
    size_t piA = ((size_t)c * 576 + (size_t)b * 72 + tile) * 2;
    size_t piB = ((size_t)(c + 32) * 576 + (size_t)b * 72 + tile) * 2;
    partF[piA] = red[0] + red[4] + red[8] + red[12];
    partF[piA + 1] = red[1] + red[5] + red[9] + red[13];
    partF[piB] = red[2] + red[6] + red[10] + red[14];
    partF[piB + 1] = red[3] + red[7] + red[11] + red[15];
  }
}

// ---------------------------------------------------------------------------
// mlrelu(affine1(x)) stats, C=64, float4. grid = 64*64.
// ---------------------------------------------------------------------------
__global__ __launch_bounds__(256) void stats_mlrelu(const float4* __restrict__ X,
                                                    const float* __restrict__ sc1,
                                                    const float* __restrict__ sh1,
                                                    float* __restrict__ part) {
  int c = blockIdx.x >> 6, s = blockIdx.x & 63;
  float a1 = sc1[c], b1 = sh1[c];
  float sum = 0.f, sq = 0.f;
  int b = s >> 3;
  const float4* Xp = X + (size_t)(b * 64 + c) * HW4 + (s & 7) * 4608 + threadIdx.x;
#pragma unroll 6
  for (int it = 0; it < 18; ++it) {
    float4 v = Xp[it * 256];
    float u;
    u = mlrelu(fmaf(v.x, a1, b1)); sum += u; sq += u * u;
    u = mlrelu(fmaf(v.y, a1, b1)); sum += u; sq += u * u;
    u = mlrelu(fmaf(v.z, a1, b1)); sum += u; sq += u * u;
    u = mlrelu(fmaf(v.w, a1, b1)); sum += u; sq += u * u;
  }
  int lane = threadIdx.x & 63, wd = threadIdx.x >> 6;
  for (int off = 32; off; off >>= 1) {
    sum += __shfl_down(sum, off);
    sq += __shfl_down(sq, off);
  }
  __shared__ float red[8];
  if (lane == 0) { red[wd * 2] = sum; red[wd * 2 + 1] = sq; }
  __syncthreads();
  if (threadIdx.x == 0) {
    part[((size_t)c * 64 + s) * 2] = red[0] + red[2] + red[4] + red[6];
    part[((size_t)c * 64 + s) * 2 + 1] = red[1] + red[3] + red[5] + red[7];
  }
}

// ---------------------------------------------------------------------------
// fused ft pass: sl stride 81; Hl float4 with XOR swizzle idx4 = r*16+(g^((r>>2)&3))
// (spreads the 4 ly-groups across bank quads). grid (36, 512).
// ---------------------------------------------------------------------------
__global__ __launch_bounds__(256) void ft_fused(const float* __restrict__ src,
                                                const float* __restrict__ F1SC,
                                                const float* __restrict__ F1SH,
                                                const float* __restrict__ F2SC,
                                                const float* __restrict__ F2SH,
                                                float* __restrict__ dst, float fscale,
                                                float* __restrict__ part) {
  __shared__ float sl[74 * 81];
  __shared__ __align__(16) float Hl[74 * 64];
  __shared__ float red[8];
  const int tile = blockIdx.x;
  const int plane = blockIdx.y;
  const int b = plane >> 6, c = plane & 63;
  const int tx = (tile % 6) * 64, ty = (tile / 6) * 64;
  const float a1 = F1SC[c], b1 = F1SH[c], a2 = F2SC[c], b2 = F2SH[c];
  const float* sp = src + (size_t)plane * HW;

  for (int i = threadIdx.x; i < 74 * 20; i += 256) {
    int r = i / 20, k = i - r * 20;
    int gy = ty + r - 5, gx = tx + k * 4 - 8;
    float4 sv = {0.f, 0.f, 0.f, 0.f};
    if (gy >= 0 && gy < WID && gx >= 0 && gx < WID) {
      float4 v = *reinterpret_cast<const float4*>(sp + (size_t)gy * WID + gx);
      sv.x = fmaf(mlrelu(fmaf(v.x, a1, b1)), a2, b2);
      sv.y = fmaf(mlrelu(fmaf(v.y, a1, b1)), a2, b2);
      sv.z = fmaf(mlrelu(fmaf(v.z, a1, b1)), a2, b2);
      sv.w = fmaf(mlrelu(fmaf(v.w, a1, b1)), a2, b2);
    }
    int base = r * 81 + k * 4;
    sl[base] = sv.x; sl[base + 1] = sv.y; sl[base + 2] = sv.z; sl[base + 3] = sv.w;
  }
  __syncthreads();

  float4* H4 = reinterpret_cast<float4*>(Hl);
  for (int i = threadIdx.x; i < 74 * 16; i += 256) {
    int r = i >> 4, g = i & 15;
    const float* s0 = &sl[r * 81 + g * 4 + 3];
    float v[14];
#pragma unroll
    for (int j = 0; j < 14; ++j) v[j] = s0[j];
    float h0 = v[0] + v[1] + v[2] + v[3] + v[4] + v[5] + v[6] + v[7] + v[8] + v[9] + v[10];
    float h1 = h0 - v[0] + v[11];
    float h2 = h1 - v[1] + v[12];
    float h3 = h2 - v[2] + v[13];
    float4 hh = {h0, h1, h2, h3};
    H4[r * 16 + (g ^ ((r >> 2) & 3))] = hh;
  }
  __syncthreads();

  const int g = threadIdx.x & 15, ly = threadIdx.x >> 4;
  const int y0 = ly * 4;
  float4 acc = H4[y0 * 16 + (g ^ ((y0 >> 2) & 3))];
#pragma unroll
  for (int dy = 1; dy < 11; ++dy) {
    int y = y0 + dy;
    float4 t = H4[y * 16 + (g ^ ((y >> 2) & 3))];
    acc.x += t.x; acc.y += t.y; acc.z += t.z; acc.w += t.w;
  }
  float sum = 0.f, sq = 0.f;
  float* dpo = dst + (size_t)plane * HW;
#pragma unroll
  for (int ry = 0; ry < 4; ++ry) {
    int y = y0 + ry;
    if (ry) {
      int ya = y + 10, yb = y - 1;
      float4 ta = H4[ya * 16 + (g ^ ((ya >> 2) & 3))];
      float4 tb = H4[yb * 16 + (g ^ ((yb >> 2) & 3))];
      acc.x += ta.x - tb.x; acc.y += ta.y - tb.y;
      acc.z += ta.z - tb.z; acc.w += ta.w - tb.w;
    }
    const float* cp = &sl[(y + 5) * 81 + g * 4 + 8];
    float4 o;
    o.x = (2.f * cp[0] - acc.x * (1.f / 121.f)) * fscale;
    o.y = (2.f * cp[1] - acc.y * (1.f / 121.f)) * fscale;
    o.z = (2.f * cp[2] - acc.z * (1.f / 121.f)) * fscale;
    o.w = (2.f * cp[3] - acc.w * (1.f / 121.f)) * fscale;
    *reinterpret_cast<float4*>(dpo + (size_t)(ty + y) * WID + tx + g * 4) = o;
    sum += o.x + o.y + o.z + o.w;
    sq += o.x * o.x + o.y * o.y + o.z * o.z + o.w * o.w;
  }
  if (part) {
    int lane = threadIdx.x & 63, wd = threadIdx.x >> 6;
    for (int off = 32; off; off >>= 1) {
      sum += __shfl_down(sum, off);
      sq += __shfl_down(sq, off);
    }
    if (lane == 0) { red[wd * 2] = sum; red[wd * 2 + 1] = sq; }
    __syncthreads();
    if (threadIdx.x == 0) {
      size_t pi = ((size_t)c * 288 + (size_t)b * 36 + tile) * 2;
      part[pi] = red[0] + red[2] + red[4] + red[6];
      part[pi + 1] = red[1] + red[3] + red[5] + red[7];
    }
  }
}

// ---------------------------------------------------------------------------
extern "C" void kernel_launch(void* const* d_in, const int* in_sizes, int n_in,
                              void* d_out, int out_size, void* d_ws, size_t ws_size,
                              hipStream_t stream) {
  const float* x     = (const float*)d_in[0];
  const float* p_w1  = (const float*)d_in[1];
  const float* p_b1  = (const float*)d_in[2];
  const float* p_dw1 = (const float*)d_in[3];
  const float* p_db1 = (const float*)d_in[4];
  const float* p_g1  = (const float*)d_in[5];
  const float* p_be1 = (const float*)d_in[6];
  const float* p_w2  = (const float*)d_in[7];
  const float* p_b2  = (const float*)d_in[8];
  const float* p_dw2 = (const float*)d_in[9];
  const float* p_db2 = (const float*)d_in[10];
  const float* p_g2  = (const float*)d_in[11];
  const float* p_be2 = (const float*)d_in[12];
  const float* d_w   = (const float*)d_in[13];
  const float* d_b   = (const float*)d_in[14];
  const float* ia_w  = (const float*)d_in[15];
  const float* ia_b  = (const float*)d_in[16];
  const float* ia_g  = (const float*)d_in[17];
  const float* ia_be = (const float*)d_in[18];
  const float* ib_w  = (const float*)d_in[19];
  const float* ib_b  = (const float*)d_in[20];
  const float* ib_g  = (const float*)d_in[21];
  const float* ib_be = (const float*)d_in[22];
  const float* f_g1  = (const float*)d_in[23];
  const float* f_be1 = (const float*)d_in[24];
  const float* f_g2  = (const float*)d_in[25];
  const float* f_be2 = (const float*)d_in[26];
  float* out = (float*)d_out;
  float* ws = (float*)d_ws;

  const size_t SLOT = 37748736ull;  // 8*32*384*384 floats; score = 2*SLOT
  float* B0 = ws;
  float* B1 = ws + 2 * SLOT;
  float* t2 = B0;
  float* partA = B0 + SLOT;                // 184,320 used [5][32][576][2]
  float* partB = partA + 368640;           // 184,320 used
  float* partP = partB + 368640;           // 147,456  [32][2304][2]
  float* part9 = partP + 147456;           // 2,304    [256][9]
  float* aff   = part9 + 2304;             // 640      [2][5][2][32]
  float* xm  = B1;                         // 3,538,944
  float* dd1 = xm + 3538944;               // 4,194,304
  float* dd2 = dd1 + 4194304;              // 473,344
  float* dd3 = dd2 + 473344;               // 57,600
  float* dd4 = dd3 + 57600;                // 6,400
  float* dd5 = dd4 + 6400;                 // 1,024
  float* partF = ws + 4 * SLOT;            // 147,456 (max used 73,728)
  float* partS = partF + 147456;           // 8,192    [64][64][2]
  float* st    = partS + 8192;             // 512
  float* geoT  = st + 512;                 // 7,680   [5][384] float4

  float* P1SC = st,       *P1SH = st + 32;
  float* P2SC = st + 64,  *P2SH = st + 96;
  float* F1SC = st + 128, *F1SH = st + 192;
  float* F2SC = st + 256, *F2SH = st + 320;

  // geometry table + mode + prepare
  geo_build<<<8, 256, 0, stream>>>((float4*)geoT);
  mode_kernel<<<dim3(6, 24, 24), 256, 0, stream>>>(x, xm);
  xm_mom<<<256, 256, 0, stream>>>((const float4*)xm, part9);
  prep1_affine<<<1, 64, 0, stream>>>(part9, p_w1, p_b1, p_dw1, p_db1, p_g1, p_be1, P1SC, P1SH);
  prep_fused<<<2304, 256, 0, stream>>>(xm, p_w1, p_b1, p_dw1, p_db1, P1SC, P1SH,
                                       p_w2, p_b2, p_dw2, p_db2, t2, partP);
  stats_combine<<<32, 64, 0, stream>>>(partP, 2304, p_g2, p_be2, P2SC, P2SH);

  // pyramid d-chain
  dconv<true><<<16384, 256, 0, stream>>>(t2, P2SC, P2SH, d_w, d_b, 384, 128, dd1,
                                         8 * 32 * 128 * 128);
  dconv<false><<<(8 * 32 * 43 * 43 + 255) / 256, 256, 0, stream>>>(
      dd1, nullptr, nullptr, d_w, d_b, 128, 43, dd2, 8 * 32 * 43 * 43);
  dconv<false><<<(8 * 32 * 15 * 15 + 255) / 256, 256, 0, stream>>>(
      dd2, nullptr, nullptr, d_w, d_b, 43, 15, dd3, 8 * 32 * 15 * 15);
  dconv<false><<<(8 * 32 * 5 * 5 + 255) / 256, 256, 0, stream>>>(
      dd3, nullptr, nullptr, d_w, d_b, 15, 5, dd4, 8 * 32 * 5 * 5);
  dconv<false><<<(8 * 32 * 2 * 2 + 255) / 256, 256, 0, stream>>>(
      dd4, nullptr, nullptr, d_w, d_b, 5, 2, dd5, 8 * 32 * 2 * 2);

  // all-level stats (64x32 tiles, 2 planes), then single-write apply
  upstats64<<<dim3(72, 128, 5), 256, 0, stream>>>(dd1, dd2, dd3, dd4, dd5,
                                                  (const float4*)geoT,
                                                  ia_w, ib_w, ia_b, ib_b, partA, partB);
  combine_lvls<<<dim3(32, 5, 2), 64, 0, stream>>>(partA, partB, ia_g, ia_be, ib_g, ib_be, aff);
  apply64<<<dim3(72, 256), 256, 0, stream>>>(dd1, dd2, dd3, dd4, dd5,
                                             (const float4*)geoT,
                                             ia_w, ib_w, ia_b, ib_b, aff, out, partF);

  // ft chain x3; rotation out -> B0 -> B1 -> out
  const float* cur = out;
  float* dsts[3] = {B0, B1, out};
  for (int k = 0; k < 3; ++k) {
    stats_combine<<<64, 64, 0, stream>>>(partF, (k == 0) ? 576 : 288, f_g1, f_be1, F1SC, F1SH);
    stats_mlrelu<<<64 * 64, 256, 0, stream>>>((const float4*)cur, F1SC, F1SH, partS);
    stats_combine<<<64, 64, 0, stream>>>(partS, 64, f_g2, f_be2, F2SC, F2SH);
    ft_fused<<<dim3(36, 512), 256, 0, stream>>>(cur, F1SC, F1SH, F2SC, F2SH, dsts[k],
                                                (k == 2) ? 0.2f : 1.0f,
                                                (k < 2) ? partF : nullptr);
    cur = dsts[k];
  }
}

// Round 12
// 1728.934 us; speedup vs baseline: 1.0527x; 1.0527x over previous
//
#include <hip/hip_runtime.h>

#define HW 147456
#define WID 384
#define NB 8
#define NPC 1179648   // per-channel element count = 8*384*384
#define HW4 36864     // HW/4
#define ZS 76         // zt/dH LDS row stride

static __device__ __forceinline__ float lrelu01(float v) { return v >= 0.f ? v : 0.01f * v; }
static __device__ __forceinline__ float mlrelu(float v) { return v > 0.1f ? 0.1f + 0.7f * (v - 0.1f) : v; }

// ---------------------------------------------------------------------------
// Mode pool (unchanged)
// ---------------------------------------------------------------------------
__global__ __launch_bounds__(256) void mode_kernel(const float* __restrict__ x,
                                                   float* __restrict__ xm) {
  __shared__ unsigned char qt[26 * 76];
  __shared__ unsigned int cc[16 * 5 * 76];
  const int plane = blockIdx.z;
  const int x0 = blockIdx.x * 64;
  const int y0 = blockIdx.y * 16;
  const float* xp = x + (size_t)plane * HW;

  for (int i = threadIdx.x; i < 26 * 76; i += 256) {
    int r = i / 76, ccol = i - r * 76;
    int gy = y0 + r - 5, gx = x0 + ccol - 5;
    unsigned char q = 0;
    if (ccol < 74 && gy >= 0 && gy < WID && gx >= 0 && gx < WID) {
      float v = xp[gy * WID + gx];
      int qi = (int)rintf(v * 15.9375f);
      qi = qi < 0 ? 0 : (qi > 16 ? 16 : qi);
      q = (unsigned char)qi;
    }
    qt[i] = q;
  }
  __syncthreads();

  for (int i = threadIdx.x; i < 16 * 74; i += 256) {
    int yy = i / 74, col = i - yy * 74;
    unsigned int w0 = 0, w1 = 0, w2 = 0, w3 = 0, w4 = 0;
#pragma unroll
    for (int dy = 0; dy < 11; ++dy) {
      int q = qt[(yy + dy) * 76 + col];
      unsigned int inc = 1u << ((q & 3) << 3);
      int wsel = q >> 2;
      w0 += (wsel == 0) ? inc : 0u;
      w1 += (wsel == 1) ? inc : 0u;
      w2 += (wsel == 2) ? inc : 0u;
      w3 += (wsel == 3) ? inc : 0u;
      w4 += (wsel == 4) ? inc : 0u;
    }
    cc[(yy * 5 + 0) * 76 + col] = w0;
    cc[(yy * 5 + 1) * 76 + col] = w1;
    cc[(yy * 5 + 2) * 76 + col] = w2;
    cc[(yy * 5 + 3) * 76 + col] = w3;
    cc[(yy * 5 + 4) * 76 + col] = w4;
  }
  __syncthreads();

  for (int i = threadIdx.x; i < 16 * 64; i += 256) {
    int yy = i / 64, xx = i - yy * 64;
    unsigned int s0 = 0, s1 = 0, s2 = 0, s3 = 0, s4 = 0;
#pragma unroll
    for (int dx = 0; dx < 11; ++dx) {
      int col = xx + dx;
      s0 += cc[(yy * 5 + 0) * 76 + col];
      s1 += cc[(yy * 5 + 1) * 76 + col];
      s2 += cc[(yy * 5 + 2) * 76 + col];
      s3 += cc[(yy * 5 + 3) * 76 + col];
      s4 += cc[(yy * 5 + 4) * 76 + col];
    }
    unsigned int words[5] = {s0, s1, s2, s3, s4};
    int best = 0;
    unsigned int bc = s0 & 0xffu;
#pragma unroll
    for (int bin = 1; bin < 17; ++bin) {
      unsigned int cnt = (words[bin >> 2] >> ((bin & 3) * 8)) & 0xffu;
      if (cnt > bc) { bc = cnt; best = bin; }
    }
    xm[(size_t)plane * HW + (size_t)(y0 + yy) * WID + (x0 + xx)] = best * 0.0625f;
  }
}

// ---------------------------------------------------------------------------
// xm second moments (unchanged)
// ---------------------------------------------------------------------------
__global__ __launch_bounds__(256) void xm_mom(const float4* __restrict__ X,
                                              float* __restrict__ part9) {
  float s0 = 0, s1 = 0, s2 = 0, m00 = 0, m01 = 0, m02 = 0, m11 = 0, m12 = 0, m22 = 0;
  const int end = (blockIdx.x + 1) * 1152;
  for (int u = blockIdx.x * 1152 + threadIdx.x; u < end; u += 256) {
    int b = u / HW4, p4 = u - b * HW4;
    const float4* base = X + (size_t)b * 3 * HW4 + p4;
    float4 a = base[0], bb = base[HW4], c = base[2 * HW4];
    s0 += a.x + a.y + a.z + a.w;
    s1 += bb.x + bb.y + bb.z + bb.w;
    s2 += c.x + c.y + c.z + c.w;
    m00 += a.x * a.x + a.y * a.y + a.z * a.z + a.w * a.w;
    m01 += a.x * bb.x + a.y * bb.y + a.z * bb.z + a.w * bb.w;
    m02 += a.x * c.x + a.y * c.y + a.z * c.z + a.w * c.w;
    m11 += bb.x * bb.x + bb.y * bb.y + bb.z * bb.z + bb.w * bb.w;
    m12 += bb.x * c.x + bb.y * c.y + bb.z * c.z + bb.w * c.w;
    m22 += c.x * c.x + c.y * c.y + c.z * c.z + c.w * c.w;
  }
  float vals[9] = {s0, s1, s2, m00, m01, m02, m11, m12, m22};
  int lane = threadIdx.x & 63, wd = threadIdx.x >> 6;
  __shared__ float red[4][9];
#pragma unroll
  for (int j = 0; j < 9; ++j) {
    float v = vals[j];
    for (int off = 32; off; off >>= 1) v += __shfl_down(v, off);
    if (lane == 0) red[wd][j] = v;
  }
  __syncthreads();
  if (threadIdx.x < 9)
    part9[blockIdx.x * 9 + threadIdx.x] =
        red[0][threadIdx.x] + red[1][threadIdx.x] + red[2][threadIdx.x] + red[3][threadIdx.x];
}

// ---------------------------------------------------------------------------
// analytic BN1 affine (unchanged)
// ---------------------------------------------------------------------------
__global__ __launch_bounds__(64) void prep1_affine(const float* __restrict__ part9,
                                                   const float* __restrict__ w1,
                                                   const float* __restrict__ b1,
                                                   const float* __restrict__ dw1,
                                                   const float* __restrict__ db1,
                                                   const float* __restrict__ g,
                                                   const float* __restrict__ be,
                                                   float* __restrict__ sc,
                                                   float* __restrict__ sh) {
  __shared__ double M[9];
  if (threadIdx.x < 9) {
    double s = 0.0;
    for (int i = 0; i < 256; ++i) s += (double)part9[i * 9 + threadIdx.x];
    M[threadIdx.x] = s;
  }
  __syncthreads();
  if (threadIdx.x < 32) {
    int o = threadIdx.x;
    double dw = dw1[o];
    double a0 = (double)w1[o * 3] * dw, a1 = (double)w1[o * 3 + 1] * dw,
           a2 = (double)w1[o * 3 + 2] * dw;
    double k = (double)b1[o] * dw + (double)db1[o];
    double N = (double)NPC;
    double lin = (a0 * M[0] + a1 * M[1] + a2 * M[2]) / N;
    double mean = lin + k;
    double e2 = (a0 * a0 * M[3] + a1 * a1 * M[6] + a2 * a2 * M[8] +
                 2.0 * (a0 * a1 * M[4] + a0 * a2 * M[5] + a1 * a2 * M[7])) / N +
                2.0 * k * lin + k * k;
    double var = e2 - mean * mean;
    float rstd = rsqrtf((float)var + 1e-5f);
    float scl = rstd * g[o];
    sc[o] = scl;
    sh[o] = be[o] - (float)mean * scl;
  }
}

// ---------------------------------------------------------------------------
// fused prepare (unchanged)
// ---------------------------------------------------------------------------
__global__ __launch_bounds__(256) void prep_fused(const float* __restrict__ xm,
                                                  const float* __restrict__ w1,
                                                  const float* __restrict__ b1,
                                                  const float* __restrict__ dw1,
                                                  const float* __restrict__ db1,
                                                  const float* __restrict__ P1SC,
                                                  const float* __restrict__ P1SH,
                                                  const float* __restrict__ w2,
                                                  const float* __restrict__ b2,
                                                  const float* __restrict__ dw2,
                                                  const float* __restrict__ db2,
                                                  float* __restrict__ t2,
                                                  float* __restrict__ part) {
  __shared__ float wl[1024];
  __shared__ float c1[32][4];
  __shared__ float bias2[32];
  __shared__ float wred[8][32];
  for (int i = threadIdx.x; i < 1024; i += 256) wl[i] = w2[i] * dw2[i >> 5];
  if (threadIdx.x < 32) {
    int o = threadIdx.x;
    float dw = dw1[o], s1 = P1SC[o];
    c1[o][0] = w1[o * 3] * dw * s1;
    c1[o][1] = w1[o * 3 + 1] * dw * s1;
    c1[o][2] = w1[o * 3 + 2] * dw * s1;
    c1[o][3] = (b1[o] * dw + db1[o]) * s1 + P1SH[o];
    bias2[o] = b2[o] * dw2[o] + db2[o];
  }
  __syncthreads();
  const int p0 = blockIdx.x * 512 + threadIdx.x;
  const int b = p0 / HW, pp = p0 - b * HW;
  const float* xb = xm + (size_t)b * 3 * HW + pp;
  float h[2][32];
#pragma unroll
  for (int q = 0; q < 2; ++q) {
    float x0 = xb[q * 256], x1 = xb[HW + q * 256], x2 = xb[2 * HW + q * 256];
#pragma unroll
    for (int o = 0; o < 32; ++o) {
      float u = fmaf(x0, c1[o][0], fmaf(x1, c1[o][1], fmaf(x2, c1[o][2], c1[o][3])));
      h[q][o] = lrelu01(u);
    }
  }
  float sv[32], sq[32];
  float* ob = t2 + (size_t)b * 32 * HW + pp;
  const float4* wl4 = reinterpret_cast<const float4*>(wl);
  for (int o = 0; o < 32; ++o) {
    float acc0 = bias2[o], acc1 = bias2[o];
#pragma unroll
    for (int c4 = 0; c4 < 8; ++c4) {
      float4 w4 = wl4[o * 8 + c4];
      int c = c4 * 4;
      acc0 = fmaf(h[0][c], w4.x, acc0);     acc1 = fmaf(h[1][c], w4.x, acc1);
      acc0 = fmaf(h[0][c + 1], w4.y, acc0); acc1 = fmaf(h[1][c + 1], w4.y, acc1);
      acc0 = fmaf(h[0][c + 2], w4.z, acc0); acc1 = fmaf(h[1][c + 2], w4.z, acc1);
      acc0 = fmaf(h[0][c + 3], w4.w, acc0); acc1 = fmaf(h[1][c + 3], w4.w, acc1);
    }
    ob[(size_t)o * HW] = acc0;
    ob[(size_t)o * HW + 256] = acc1;
    sv[o] = acc0 + acc1;
    sq[o] = acc0 * acc0 + acc1 * acc1;
  }
  int lane = threadIdx.x & 63, wd = threadIdx.x >> 6;
#pragma unroll
  for (int o = 0; o < 32; ++o) {
    float a = sv[o], q = sq[o];
    for (int off = 32; off; off >>= 1) {
      a += __shfl_down(a, off);
      q += __shfl_down(q, off);
    }
    if (lane == 0) { wred[wd][o] = a; wred[wd + 4][o] = q; }
  }
  __syncthreads();
  if (threadIdx.x < 32) {
    int o = threadIdx.x;
    part[((size_t)o * 2304 + blockIdx.x) * 2] = wred[0][o] + wred[1][o] + wred[2][o] + wred[3][o];
    part[((size_t)o * 2304 + blockIdx.x) * 2 + 1] = wred[4][o] + wred[5][o] + wred[6][o] + wred[7][o];
  }
}

// ---------------------------------------------------------------------------
// combine partials -> folded affine (unchanged)
// ---------------------------------------------------------------------------
__global__ __launch_bounds__(64) void stats_combine(const float* __restrict__ part, int nsplit,
                                                    const float* __restrict__ g,
                                                    const float* __restrict__ be,
                                                    float* __restrict__ sc,
                                                    float* __restrict__ sh) {
  const int c = blockIdx.x;
  double s = 0.0, q = 0.0;
  for (int i = threadIdx.x; i < nsplit; i += 64) {
    s += part[((size_t)c * nsplit + i) * 2];
    q += part[((size_t)c * nsplit + i) * 2 + 1];
  }
  for (int off = 32; off; off >>= 1) {
    s += __shfl_down(s, off);
    q += __shfl_down(q, off);
  }
  if (threadIdx.x == 0) {
    double mean = s / (double)NPC;
    double var = q / (double)NPC - mean * mean;
    float rstd = rsqrtf((float)var + 1e-5f);
    float scl = rstd * g[c];
    sc[c] = scl;
    sh[c] = be[c] - (float)mean * scl;
  }
}

// ---------------------------------------------------------------------------
// shared depthwise 3x3 stride-3 pad-1 conv (unchanged)
// ---------------------------------------------------------------------------
template <bool AFF>
__global__ __launch_bounds__(256) void dconv(const float* __restrict__ in,
                                             const float* __restrict__ sc,
                                             const float* __restrict__ sh,
                                             const float* __restrict__ w9,
                                             const float* __restrict__ db,
                                             int Sin, int Sout,
                                             float* __restrict__ out, int total) {
  int idx = blockIdx.x * 256 + threadIdx.x;
  if (idx >= total) return;
  int xx = idx % Sout;
  int t = idx / Sout;
  int yy = t % Sout;
  int pc = t / Sout;
  int c = pc & 31;
  const float* ip = in + (size_t)pc * Sin * Sin;
  float a = AFF ? sc[c] : 1.f;
  float h = AFF ? sh[c] : 0.f;
  float acc = 0.f;
#pragma unroll
  for (int ky = 0; ky < 3; ++ky) {
    int iy = 3 * yy - 1 + ky;
    if (iy < 0 || iy >= Sin) continue;
#pragma unroll
    for (int kx = 0; kx < 3; ++kx) {
      int ix = 3 * xx - 1 + kx;
      if (ix < 0 || ix >= Sin) continue;
      float v = ip[(size_t)iy * Sin + ix];
      if (AFF) { v = v * a + h; v = lrelu01(v); }
      acc = fmaf(v, w9[ky * 3 + kx], acc);
    }
  }
  out[idx] = acc + db[0];
}

// ---------------------------------------------------------------------------
// geometry table
// ---------------------------------------------------------------------------
static __device__ __forceinline__ int sin_of(int l) {
  return l == 0 ? 128 : l == 1 ? 43 : l == 2 ? 15 : l == 3 ? 5 : 2;
}

__global__ __launch_bounds__(256) void geo_build(float4* __restrict__ geo) {
  int id = blockIdx.x * 256 + threadIdx.x;
  if (id >= 5 * 384) return;
  int l = id / 384, p = id - l * 384;
  int Sin = sin_of(l);
  float scale = (float)Sin / 384.f;
  float s = (p + 0.5f) * scale - 0.5f;
  float f0 = floorf(s);
  float fr = s - f0;
  int ii = (int)f0;
  int i1 = ii + 1 < Sin - 1 ? ii + 1 : Sin - 1;
  int i0 = ii > 0 ? ii : 0;
  geo[id] = make_float4((float)i0, (float)i1, fr, 0.f);
}

static __device__ __forceinline__ int clamp383(int v) {
  return v < 0 ? 0 : (v > 383 ? 383 : v);
}

// ---------------------------------------------------------------------------
// 4-row streaming 5x5 dual conv: thread owns output rows 4u..4u+3, cols 4g..4g+3.
// Streams z rows 4u..4u+7 (one row live at a time), 16 b128 reads, 800 FMA.
// ---------------------------------------------------------------------------
__device__ __forceinline__ void conv4row(const float* zt, int u, int g,
                                         const float* wa, const float* wb,
                                         float ba0, float bb0,
                                         float A[4][4], float Bv[4][4]) {
#pragma unroll
  for (int j = 0; j < 4; ++j)
#pragma unroll
    for (int p = 0; p < 4; ++p) { A[j][p] = ba0; Bv[j][p] = bb0; }
  const float* zp = zt + (4 * u) * ZS + g * 4;
#pragma unroll
  for (int zr = 0; zr < 8; ++zr) {
    float4 zlo = *reinterpret_cast<const float4*>(zp + zr * ZS);
    float4 zhi = *reinterpret_cast<const float4*>(zp + zr * ZS + 4);
    float z[8] = {zlo.x, zlo.y, zlo.z, zlo.w, zhi.x, zhi.y, zhi.z, zhi.w};
#pragma unroll
    for (int j = 0; j < 4; ++j) {
      int dy = zr - j;
      if (dy >= 0 && dy <= 4) {
#pragma unroll
        for (int dx = 0; dx < 5; ++dx) {
          float wva = wa[dy * 5 + dx], wvb = wb[dy * 5 + dx];
#pragma unroll
          for (int p = 0; p < 4; ++p) {
            A[j][p] = fmaf(z[dx + p], wva, A[j][p]);
            Bv[j][p] = fmaf(z[dx + p], wvb, Bv[j][p]);
          }
        }
      }
    }
  }
}

// shared staging: 64x64 tile (+4 halo): dH <=26 rows, zt 68 rows.
__device__ __forceinline__ void stage64(float* zt, float* dH, const float* dp, int Sin,
                                        const float4* xg, int tx, int ty,
                                        int rowlo, int nr) {
  for (int i = threadIdx.x; i < nr * 68; i += 256) {
    int r = i / 68, zx = i - r * 68;
    int gp = tx + zx - 2;
    int gpc = clamp383(gp);
    float vd = (gp == gpc) ? 1.f : 0.f;
    float4 ge = xg[gpc];
    const float* drow = dp + (size_t)(rowlo + r) * Sin;
    float v0 = drow[(int)ge.x], v1 = drow[(int)ge.y];
    dH[r * ZS + zx] = (v0 + ge.z * (v1 - v0)) * vd;
  }
  __syncthreads();
  for (int i = threadIdx.x; i < 68 * 17; i += 256) {
    int zy = i / 17, k = i - zy * 17;
    int gp = ty + zy - 2;
    int gpc = clamp383(gp);
    float vd = (gp == gpc) ? 1.f : 0.f;
    float4 ge = xg[gpc];
    int r0 = (int)ge.x - rowlo, r1 = (int)ge.y - rowlo;
    float fy = ge.z;
    float4 a4 = *reinterpret_cast<const float4*>(&dH[r0 * ZS + k * 4]);
    float4 b4 = *reinterpret_cast<const float4*>(&dH[r1 * ZS + k * 4]);
    float4 o;
    o.x = (a4.x + fy * (b4.x - a4.x)) * vd;
    o.y = (a4.y + fy * (b4.y - a4.y)) * vd;
    o.z = (a4.z + fy * (b4.z - a4.z)) * vd;
    o.w = (a4.w + fy * (b4.w - a4.w)) * vd;
    *reinterpret_cast<float4*>(&zt[zy * ZS + k * 4]) = o;
  }
}

// ---------------------------------------------------------------------------
// pyramid stats: 64x64 tile, 1 plane/block. grid (36, 256, 5).
// ---------------------------------------------------------------------------
__global__ __launch_bounds__(256) void upstats64(const float* __restrict__ d1,
                                                 const float* __restrict__ d2,
                                                 const float* __restrict__ d3,
                                                 const float* __restrict__ d4,
                                                 const float* __restrict__ d5,
                                                 const float4* __restrict__ geo,
                                                 const float* __restrict__ wA5,
                                                 const float* __restrict__ wB5,
                                                 const float* __restrict__ bA,
                                                 const float* __restrict__ bB,
                                                 float* __restrict__ partA,
                                                 float* __restrict__ partB) {
  __shared__ __align__(16) float zt[68 * ZS];
  __shared__ __align__(16) float dH[26 * ZS];
  __shared__ float red[16];
  const int lvl = blockIdx.z;
  const float* dsel = lvl == 0 ? d1 : lvl == 1 ? d2 : lvl == 2 ? d3 : lvl == 3 ? d4 : d5;
  const int Sin = sin_of(lvl);
  const int plane = blockIdx.y, tile = blockIdx.x;
  const int tx = (tile % 6) * 64, ty = (tile / 6) * 64;
  const float4* xg = geo + lvl * 384;
  const float* dp = dsel + (size_t)plane * Sin * Sin;

  float wa[25], wb[25];
#pragma unroll
  for (int k = 0; k < 25; ++k) { wa[k] = wA5[k]; wb[k] = wB5[k]; }
  const float ba0 = bA[0], bb0 = bB[0];

  const int rowlo = (int)xg[clamp383(ty - 2)].x;
  const int rowhi = (int)xg[clamp383(ty + 65)].y;
  const int nr = rowhi - rowlo + 1;

  stage64(zt, dH, dp, Sin, xg, tx, ty, rowlo, nr);
  __syncthreads();

  const int u = threadIdx.x >> 4, g = threadIdx.x & 15;
  float A[4][4], Bv[4][4];
  conv4row(zt, u, g, wa, wb, ba0, bb0, A, Bv);
  float sa = 0.f, qa = 0.f, sb = 0.f, qb = 0.f;
#pragma unroll
  for (int j = 0; j < 4; ++j)
#pragma unroll
    for (int p = 0; p < 4; ++p) {
      sa += A[j][p]; qa += A[j][p] * A[j][p];
      sb += Bv[j][p]; qb += Bv[j][p] * Bv[j][p];
    }
  int lane = threadIdx.x & 63, wd = threadIdx.x >> 6;
  for (int off = 32; off; off >>= 1) {
    sa += __shfl_down(sa, off); qa += __shfl_down(qa, off);
    sb += __shfl_down(sb, off); qb += __shfl_down(qb, off);
  }
  if (lane == 0) {
    red[wd * 4 + 0] = sa; red[wd * 4 + 1] = qa;
    red[wd * 4 + 2] = sb; red[wd * 4 + 3] = qb;
  }
  __syncthreads();
  if (threadIdx.x == 0) {
    int b = plane >> 5, c = plane & 31;
    size_t pi = ((size_t)lvl * 32 + c) * 288 * 2 + ((size_t)b * 36 + tile) * 2;
    partA[pi] = red[0] + red[4] + red[8] + red[12];
    partA[pi + 1] = red[1] + red[5] + red[9] + red[13];
    partB[pi] = red[2] + red[6] + red[10] + red[14];
    partB[pi + 1] = red[3] + red[7] + red[11] + red[15];
  }
}

// combine all 10 (level, conv) BN affines. grid (32, 5, 2). entries=288.
__global__ __launch_bounds__(64) void combine_lvls(const float* __restrict__ partA,
                                                   const float* __restrict__ partB,
                                                   const float* __restrict__ ia_g,
                                                   const float* __restrict__ ia_be,
                                                   const float* __restrict__ ib_g,
                                                   const float* __restrict__ ib_be,
                                                   float* __restrict__ aff) {
  const int c = blockIdx.x, lvl = blockIdx.y, z = blockIdx.z;
  const float* part = (z ? partB : partA) + (size_t)lvl * 32 * 288 * 2;
  const float* g = z ? ib_g : ia_g;
  const float* be = z ? ib_be : ia_be;
  double s = 0.0, q = 0.0;
  for (int i = threadIdx.x; i < 288; i += 64) {
    s += part[((size_t)c * 288 + i) * 2];
    q += part[((size_t)c * 288 + i) * 2 + 1];
  }
  for (int off = 32; off; off >>= 1) {
    s += __shfl_down(s, off);
    q += __shfl_down(q, off);
  }
  if (threadIdx.x == 0) {
    double mean = s / (double)NPC;
    double var = q / (double)NPC - mean * mean;
    float rstd = rsqrtf((float)var + 1e-5f);
    float scl = rstd * g[c];
    aff[((z * 5 + lvl) * 2 + 0) * 32 + c] = scl;
    aff[((z * 5 + lvl) * 2 + 1) * 32 + c] = be[c] - (float)mean * scl;
  }
}

// ---------------------------------------------------------------------------
// apply ALL 5 levels: 64x64 tile, 16 px/thread. grid (36, 256).
// ---------------------------------------------------------------------------
__global__ __launch_bounds__(256) void apply64(const float* __restrict__ d1,
                                               const float* __restrict__ d2,
                                               const float* __restrict__ d3,
                                               const float* __restrict__ d4,
                                               const float* __restrict__ d5,
                                               const float4* __restrict__ geo,
                                               const float* __restrict__ wA5,
                                               const float* __restrict__ wB5,
                                               const float* __restrict__ bA,
                                               const float* __restrict__ bB,
                                               const float* __restrict__ aff,
                                               float* __restrict__ outp,
                                               float* __restrict__ partF) {
  __shared__ __align__(16) float zt[68 * ZS];
  __shared__ __align__(16) float dH[26 * ZS];
  __shared__ float red[16];
  const int plane = blockIdx.y, tile = blockIdx.x;
  const int tx = (tile % 6) * 64, ty = (tile / 6) * 64;
  const int b = plane >> 5, c = plane & 31;
  float wa[25], wb[25];
#pragma unroll
  for (int k = 0; k < 25; ++k) { wa[k] = wA5[k]; wb[k] = wB5[k]; }
  const float ba0 = bA[0], bb0 = bB[0];
  const int u = threadIdx.x >> 4, g = threadIdx.x & 15;

  float acA[4][4], acB[4][4];
#pragma unroll
  for (int j = 0; j < 4; ++j)
#pragma unroll
    for (int p = 0; p < 4; ++p) { acA[j][p] = 0.f; acB[j][p] = 0.f; }

  for (int l = 0; l < 5; ++l) {
    const float* dsel = l == 0 ? d1 : l == 1 ? d2 : l == 2 ? d3 : l == 3 ? d4 : d5;
    const int Sin = sin_of(l);
    const float* dp = dsel + (size_t)plane * Sin * Sin;
    const float4* xg = geo + l * 384;
    const int rowlo = (int)xg[clamp383(ty - 2)].x;
    const int rowhi = (int)xg[clamp383(ty + 65)].y;
    const int nr = rowhi - rowlo + 1;
    stage64(zt, dH, dp, Sin, xg, tx, ty, rowlo, nr);
    __syncthreads();
    float A[4][4], Bv[4][4];
    conv4row(zt, u, g, wa, wb, ba0, bb0, A, Bv);
    float as = aff[(l * 2 + 0) * 32 + c], ah = aff[(l * 2 + 1) * 32 + c];
    float bs = aff[((5 + l) * 2 + 0) * 32 + c], bh = aff[((5 + l) * 2 + 1) * 32 + c];
#pragma unroll
    for (int j = 0; j < 4; ++j)
#pragma unroll
      for (int p = 0; p < 4; ++p) {
        acA[j][p] += lrelu01(fmaf(A[j][p], as, ah));
        acB[j][p] += lrelu01(fmaf(Bv[j][p], bs, bh));
      }
    __syncthreads();  // zt/dH reuse next level
  }

  size_t po = (size_t)(b * 64 + c) * HW + (size_t)(ty + 4 * u) * WID + tx + g * 4;
  float sa = 0.f, qa = 0.f, sb = 0.f, qb = 0.f;
#pragma unroll
  for (int j = 0; j < 4; ++j) {
    float4 xa = {acA[j][0], acA[j][1], acA[j][2], acA[j][3]};
    float4 xb = {acB[j][0], acB[j][1], acB[j][2], acB[j][3]};
    *reinterpret_cast<float4*>(outp + po + (size_t)j * WID) = xa;
    *reinterpret_cast<float4*>(outp + po + (size_t)32 * HW + (size_t)j * WID) = xb;
#pragma unroll
    for (int p = 0; p < 4; ++p) {
      sa += acA[j][p]; qa += acA[j][p] * acA[j][p];
      sb += acB[j][p]; qb += acB[j][p] * acB[j][p];
    }
  }
  int lane = threadIdx.x & 63, wd = threadIdx.x >> 6;
  for (int off = 32; off; off >>= 1) {
    sa += __shfl_down(sa, off); qa += __shfl_down(qa, off);
    sb += __shfl_down(sb, off); qb += __shfl_down(qb, off);
  }
  if (lane == 0) {
    red[wd * 4 + 0] = sa; red[wd * 4 + 1] = qa;
    red[wd * 4 + 2] = sb; red[wd * 4 + 3] = qb;
  }
  __syncthreads();
  if (threadIdx.x == 0) {
    size_t piA = ((size_t)c * 288 + (size_t)b * 36 + tile) * 2;
    size_t piB = ((size_t)(c + 32) * 288 + (size_t)b * 36 + tile) * 2;
    partF[piA] = red[0] + red[4] + red[8] + red[12];
    partF[piA + 1] = red[1] + red[5] + red[9] + red[13];
    partF[piB] = red[2] + red[6] + red[10] + red[14];
    partF[piB + 1] = red[3] + red[7] + red[11] + red[15];
  }
}

// ---------------------------------------------------------------------------
// mlrelu(affine1(x)) stats (unchanged)
// ---------------------------------------------------------------------------
__global__ __launch_bounds__(256) void stats_mlrelu(const float4* __restrict__ X,
                                                    const float* __restrict__ sc1,
                                                    const float* __restrict__ sh1,
                                                    float* __restrict__ part) {
  int c = blockIdx.x >> 6, s = blockIdx.x & 63;
  float a1 = sc1[c], b1 = sh1[c];
  float sum = 0.f, sq = 0.f;
  int b = s >> 3;
  const float4* Xp = X + (size_t)(b * 64 + c) * HW4 + (s & 7) * 4608 + threadIdx.x;
#pragma unroll 6
  for (int it = 0; it < 18; ++it) {
    float4 v = Xp[it * 256];
    float u;
    u = mlrelu(fmaf(v.x, a1, b1)); sum += u; sq += u * u;
    u = mlrelu(fmaf(v.y, a1, b1)); sum += u; sq += u * u;
    u = mlrelu(fmaf(v.z, a1, b1)); sum += u; sq += u * u;
    u = mlrelu(fmaf(v.w, a1, b1)); sum += u; sq += u * u;
  }
  int lane = threadIdx.x & 63, wd = threadIdx.x >> 6;
  for (int off = 32; off; off >>= 1) {
    sum += __shfl_down(sum, off);
    sq += __shfl_down(sq, off);
  }
  __shared__ float red[8];
  if (lane == 0) { red[wd * 2] = sum; red[wd * 2 + 1] = sq; }
  __syncthreads();
  if (threadIdx.x == 0) {
    part[((size_t)c * 64 + s) * 2] = red[0] + red[2] + red[4] + red[6];
    part[((size_t)c * 64 + s) * 2 + 1] = red[1] + red[3] + red[5] + red[7];
  }
}

// ---------------------------------------------------------------------------
// fused ft pass (round-11 version, unchanged)
// ---------------------------------------------------------------------------
__global__ __launch_bounds__(256) void ft_fused(const float* __restrict__ src,
                                                const float* __restrict__ F1SC,
                                                const float* __restrict__ F1SH,
                                                const float* __restrict__ F2SC,
                                                const float* __restrict__ F2SH,
                                                float* __restrict__ dst, float fscale,
                                                float* __restrict__ part) {
  __shared__ float sl[74 * 81];
  __shared__ __align__(16) float Hl[74 * 64];
  __shared__ float red[8];
  const int tile = blockIdx.x;
  const int plane = blockIdx.y;
  const int b = plane >> 6, c = plane & 63;
  const int tx = (tile % 6) * 64, ty = (tile / 6) * 64;
  const float a1 = F1SC[c], b1 = F1SH[c], a2 = F2SC[c], b2 = F2SH[c];
  const float* sp = src + (size_t)plane * HW;

  for (int i = threadIdx.x; i < 74 * 20; i += 256) {
    int r = i / 20, k = i - r * 20;
    int gy = ty + r - 5, gx = tx + k * 4 - 8;
    float4 sv = {0.f, 0.f, 0.f, 0.f};
    if (gy >= 0 && gy < WID && gx >= 0 && gx < WID) {
      float4 v = *reinterpret_cast<const float4*>(sp + (size_t)gy * WID + gx);
      sv.x = fmaf(mlrelu(fmaf(v.x, a1, b1)), a2, b2);
      sv.y = fmaf(mlrelu(fmaf(v.y, a1, b1)), a2, b2);
      sv.z = fmaf(mlrelu(fmaf(v.z, a1, b1)), a2, b2);
      sv.w = fmaf(mlrelu(fmaf(v.w, a1, b1)), a2, b2);
    }
    int base = r * 81 + k * 4;
    sl[base] = sv.x; sl[base + 1] = sv.y; sl[base + 2] = sv.z; sl[base + 3] = sv.w;
  }
  __syncthreads();

  float4* H4 = reinterpret_cast<float4*>(Hl);
  for (int i = threadIdx.x; i < 74 * 16; i += 256) {
    int r = i >> 4, g = i & 15;
    const float* s0 = &sl[r * 81 + g * 4 + 3];
    float v[14];
#pragma unroll
    for (int j = 0; j < 14; ++j) v[j] = s0[j];
    float h0 = v[0] + v[1] + v[2] + v[3] + v[4] + v[5] + v[6] + v[7] + v[8] + v[9] + v[10];
    float h1 = h0 - v[0] + v[11];
    float h2 = h1 - v[1] + v[12];
    float h3 = h2 - v[2] + v[13];
    float4 hh = {h0, h1, h2, h3};
    H4[r * 16 + (g ^ ((r >> 2) & 3))] = hh;
  }
  __syncthreads();

  const int g = threadIdx.x & 15, ly = threadIdx.x >> 4;
  const int y0 = ly * 4;
  float4 acc = H4[y0 * 16 + (g ^ ((y0 >> 2) & 3))];
#pragma unroll
  for (int dy = 1; dy < 11; ++dy) {
    int y = y0 + dy;
    float4 t = H4[y * 16 + (g ^ ((y >> 2) & 3))];
    acc.x += t.x; acc.y += t.y; acc.z += t.z; acc.w += t.w;
  }
  float sum = 0.f, sq = 0.f;
  float* dpo = dst + (size_t)plane * HW;
#pragma unroll
  for (int ry = 0; ry < 4; ++ry) {
    int y = y0 + ry;
    if (ry) {
      int ya = y + 10, yb = y - 1;
      float4 ta = H4[ya * 16 + (g ^ ((ya >> 2) & 3))];
      float4 tb = H4[yb * 16 + (g ^ ((yb >> 2) & 3))];
      acc.x += ta.x - tb.x; acc.y += ta.y - tb.y;
      acc.z += ta.z - tb.z; acc.w += ta.w - tb.w;
    }
    const float* cp = &sl[(y + 5) * 81 + g * 4 + 8];
    float4 o;
    o.x = (2.f * cp[0] - acc.x * (1.f / 121.f)) * fscale;
    o.y = (2.f * cp[1] - acc.y * (1.f / 121.f)) * fscale;
    o.z = (2.f * cp[2] - acc.z * (1.f / 121.f)) * fscale;
    o.w = (2.f * cp[3] - acc.w * (1.f / 121.f)) * fscale;
    *reinterpret_cast<float4*>(dpo + (size_t)(ty + y) * WID + tx + g * 4) = o;
    sum += o.x + o.y + o.z + o.w;
    sq += o.x * o.x + o.y * o.y + o.z * o.z + o.w * o.w;
  }
  if (part) {
    int lane = threadIdx.x & 63, wd = threadIdx.x >> 6;
    for (int off = 32; off; off >>= 1) {
      sum += __shfl_down(sum, off);
      sq += __shfl_down(sq, off);
    }
    if (lane == 0) { red[wd * 2] = sum; red[wd * 2 + 1] = sq; }
    __syncthreads();
    if (threadIdx.x == 0) {
      size_t pi = ((size_t)c * 288 + (size_t)b * 36 + tile) * 2;
      part[pi] = red[0] + red[2] + red[4] + red[6];
      part[pi + 1] = red[1] + red[3] + red[5] + red[7];
    }
  }
}

// ---------------------------------------------------------------------------
extern "C" void kernel_launch(void* const* d_in, const int* in_sizes, int n_in,
                              void* d_out, int out_size, void* d_ws, size_t ws_size,
                              hipStream_t stream) {
  const float* x     = (const float*)d_in[0];
  const float* p_w1  = (const float*)d_in[1];
  const float* p_b1  = (const float*)d_in[2];
  const float* p_dw1 = (const float*)d_in[3];
  const float* p_db1 = (const float*)d_in[4];
  const float* p_g1  = (const float*)d_in[5];
  const float* p_be1 = (const float*)d_in[6];
  const float* p_w2  = (const float*)d_in[7];
  const float* p_b2  = (const float*)d_in[8];
  const float* p_dw2 = (const float*)d_in[9];
  const float* p_db2 = (const float*)d_in[10];
  const float* p_g2  = (const float*)d_in[11];
  const float* p_be2 = (const float*)d_in[12];
  const float* d_w   = (const float*)d_in[13];
  const float* d_b   = (const float*)d_in[14];
  const float* ia_w  = (const float*)d_in[15];
  const float* ia_b  = (const float*)d_in[16];
  const float* ia_g  = (const float*)d_in[17];
  const float* ia_be = (const float*)d_in[18];
  const float* ib_w  = (const float*)d_in[19];
  const float* ib_b  = (const float*)d_in[20];
  const float* ib_g  = (const float*)d_in[21];
  const float* ib_be = (const float*)d_in[22];
  const float* f_g1  = (const float*)d_in[23];
  const float* f_be1 = (const float*)d_in[24];
  const float* f_g2  = (const float*)d_in[25];
  const float* f_be2 = (const float*)d_in[26];
  float* out = (float*)d_out;
  float* ws = (float*)d_ws;

  const size_t SLOT = 37748736ull;  // 8*32*384*384 floats; score = 2*SLOT
  float* B0 = ws;
  float* B1 = ws + 2 * SLOT;
  float* t2 = B0;
  float* partA = B0 + SLOT;                // [5][32][288][2] = 92,160
  float* partB = partA + 368640;
  float* partP = partB + 368640;           // 147,456  [32][2304][2]
  float* part9 = partP + 147456;           // 2,304
  float* aff   = part9 + 2304;             // 640
  float* xm  = B1;                         // 3,538,944
  float* dd1 = xm + 3538944;               // 4,194,304
  float* dd2 = dd1 + 4194304;              // 473,344
  float* dd3 = dd2 + 473344;               // 57,600
  float* dd4 = dd3 + 57600;                // 6,400
  float* dd5 = dd4 + 6400;                 // 1,024
  float* partF = ws + 4 * SLOT;            // [64][288][2] = 36,864
  float* partS = partF + 147456;           // 8,192
  float* st    = partS + 8192;             // 512
  float* geoT  = st + 512;                 // 7,680  [5][384] float4

  float* P1SC = st,       *P1SH = st + 32;
  float* P2SC = st + 64,  *P2SH = st + 96;
  float* F1SC = st + 128, *F1SH = st + 192;
  float* F2SC = st + 256, *F2SH = st + 320;

  // geometry table + mode + prepare
  geo_build<<<8, 256, 0, stream>>>((float4*)geoT);
  mode_kernel<<<dim3(6, 24, 24), 256, 0, stream>>>(x, xm);
  xm_mom<<<256, 256, 0, stream>>>((const float4*)xm, part9);
  prep1_affine<<<1, 64, 0, stream>>>(part9, p_w1, p_b1, p_dw1, p_db1, p_g1, p_be1, P1SC, P1SH);
  prep_fused<<<2304, 256, 0, stream>>>(xm, p_w1, p_b1, p_dw1, p_db1, P1SC, P1SH,
                                       p_w2, p_b2, p_dw2, p_db2, t2, partP);
  stats_combine<<<32, 64, 0, stream>>>(partP, 2304, p_g2, p_be2, P2SC, P2SH);

  // pyramid d-chain
  dconv<true><<<16384, 256, 0, stream>>>(t2, P2SC, P2SH, d_w, d_b, 384, 128, dd1,
                                         8 * 32 * 128 * 128);
  dconv<false><<<(8 * 32 * 43 * 43 + 255) / 256, 256, 0, stream>>>(
      dd1, nullptr, nullptr, d_w, d_b, 128, 43, dd2, 8 * 32 * 43 * 43);
  dconv<false><<<(8 * 32 * 15 * 15 + 255) / 256, 256, 0, stream>>>(
      dd2, nullptr, nullptr, d_w, d_b, 43, 15, dd3, 8 * 32 * 15 * 15);
  dconv<false><<<(8 * 32 * 5 * 5 + 255) / 256, 256, 0, stream>>>(
      dd3, nullptr, nullptr, d_w, d_b, 15, 5, dd4, 8 * 32 * 5 * 5);
  dconv<false><<<(8 * 32 * 2 * 2 + 255) / 256, 256, 0, stream>>>(
      dd4, nullptr, nullptr, d_w, d_b, 5, 2, dd5, 8 * 32 * 2 * 2);

  // all-level stats (64x64 tiles), then single-write apply
  upstats64<<<dim3(36, 256, 5), 256, 0, stream>>>(dd1, dd2, dd3, dd4, dd5,
                                                  (const float4*)geoT,
                                                  ia_w, ib_w, ia_b, ib_b, partA, partB);
  combine_lvls<<<dim3(32, 5, 2), 64, 0, stream>>>(partA, partB, ia_g, ia_be, ib_g, ib_be, aff);
  apply64<<<dim3(36, 256), 256, 0, stream>>>(dd1, dd2, dd3, dd4, dd5,
                                             (const float4*)geoT,
                                             ia_w, ib_w, ia_b, ib_b, aff, out, partF);

  // ft chain x3; rotation out -> B0 -> B1 -> out
  const float* cur = out;
  float* dsts[3] = {B0, B1, out};
  for (int k = 0; k < 3; ++k) {
    stats_combine<<<64, 64, 0, stream>>>(partF, 288, f_g1, f_be1, F1SC, F1SH);
    stats_mlrelu<<<64 * 64, 256, 0, stream>>>((const float4*)cur, F1SC, F1SH, partS);
    stats_combine<<<64, 64, 0, stream>>>(partS, 64, f_g2, f_be2, F2SC, F2SH);
    ft_fused<<<dim3(36, 512), 256, 0, stream>>>(cur, F1SC, F1SH, F2SC, F2SH, dsts[k],
                                                (k == 2) ? 0.2f : 1.0f,
                                                (k < 2) ? partF : nullptr);
    cur = dsts[k];
  }
}